// Round 1
// baseline (98.031 us; speedup 1.0000x reference)
//
#include <hip/hip_runtime.h>
#include <hip/hip_bf16.h>

// FuzzyAND: out[b,j] = max(0, 1 - sum_i sigmoid(W)[i,j] * (1 - xs[b,i]))
// B=4096, IN=1024, OUT=1024, fp32 in/out.
// Strategy: bf16 MFMA GEMM (m97-style 128x128 tile, global_load_lds staging).
// ws layout: [0, 8MB) A_bf16 (4096x1024), [8MB, 10MB) WT_bf16 (1024x1024, N-major).

constexpr int Bsz = 4096;
constexpr int IN  = 1024;
constexpr int OUT = 1024;

constexpr int BM = 128;
constexpr int BN = 128;
constexpr int BK = 32;

typedef __attribute__((ext_vector_type(8))) short bf16x8;  // 8 bf16 = 4 VGPRs
typedef __attribute__((ext_vector_type(4))) float f32x4;

__device__ inline unsigned short f2bf(float f) {
    union { float f; unsigned u; } c{f};
    unsigned lsb = (c.u >> 16) & 1u;
    unsigned r = c.u + 0x7fffu + lsb;   // round-to-nearest-even
    return (unsigned short)(r >> 16);
}

// ---- prep A: A_bf16[b][i] = bf16(1 - xs[b][i]) ----
__global__ void prep_a(const float* __restrict__ xs, unsigned short* __restrict__ A) {
    int idx = blockIdx.x * blockDim.x + threadIdx.x;  // one float4 per thread
    float4 v = ((const float4*)xs)[idx];
    ushort4 o;
    o.x = f2bf(1.0f - v.x);
    o.y = f2bf(1.0f - v.y);
    o.z = f2bf(1.0f - v.z);
    o.w = f2bf(1.0f - v.w);
    ((ushort4*)A)[idx] = o;
}

// ---- prep W: WT_bf16[o][i] = bf16(sigmoid(weights[i][o])), 32x32 LDS transpose ----
__global__ void prep_w(const float* __restrict__ w, unsigned short* __restrict__ WT) {
    __shared__ unsigned short t[32][33];
    int i0 = blockIdx.y * 32, o0 = blockIdx.x * 32;
    int tx = threadIdx.x & 31, ty = threadIdx.x >> 5;  // 32 wide x 8 high
#pragma unroll
    for (int r = 0; r < 4; ++r) {
        int row = ty + r * 8;  // i-local
        float v = w[(size_t)(i0 + row) * OUT + o0 + tx];
        float s = 1.0f / (1.0f + expf(-v));
        t[row][tx] = f2bf(s);
    }
    __syncthreads();
#pragma unroll
    for (int r = 0; r < 4; ++r) {
        int row = ty + r * 8;  // o-local
        WT[(size_t)(o0 + row) * IN + i0 + tx] = t[tx][row];
    }
}

__device__ inline void load_lds16(const unsigned short* g, unsigned short* l) {
    __builtin_amdgcn_global_load_lds(
        (const __attribute__((address_space(1))) void*)g,
        (__attribute__((address_space(3))) void*)l, 16, 0, 0);
}

// ---- GEMM: C[m][n] = max(0, 1 - sum_k A[m][k] * WT[n][k]) ----
__global__ __launch_bounds__(256) void gemm_fuzzy(const unsigned short* __restrict__ A,
                                                  const unsigned short* __restrict__ Bt,
                                                  float* __restrict__ C) {
    __shared__ unsigned short As[BM * BK];  // [m][k], 8 KB
    __shared__ unsigned short Bs[BN * BK];  // [n][k], 8 KB

    const int tid  = threadIdx.x;
    const int lane = tid & 63;
    const int wave = tid >> 6;
    const int quad = lane >> 4;
    const int l16  = lane & 15;
    const int wm   = (wave >> 1) * 64;   // wave's m-offset within tile
    const int wn   = (wave & 1) * 64;    // wave's n-offset within tile
    const int bm   = blockIdx.y * BM;
    const int bn   = blockIdx.x * BN;

    // staging: thread t fetches 16B (8 bf16): row = t>>2 (0..63), colblk = (t&3)*8
    const int srow = tid >> 2;
    const int scol = (tid & 3) * 8;
    const unsigned short* Ag = A  + (size_t)(bm + srow) * IN + scol;
    const unsigned short* Bg = Bt + (size_t)(bn + srow) * IN + scol;
    unsigned short* AsD0 = &As[tid * 8];          // rows 0..63
    unsigned short* AsD1 = &As[2048 + tid * 8];   // rows 64..127
    unsigned short* BsD0 = &Bs[tid * 8];
    unsigned short* BsD1 = &Bs[2048 + tid * 8];

    f32x4 acc[4][4] = {};

    for (int k0 = 0; k0 < IN; k0 += BK) {
        load_lds16(Ag + k0,            AsD0);
        load_lds16(Ag + 64 * IN + k0,  AsD1);
        load_lds16(Bg + k0,            BsD0);
        load_lds16(Bg + 64 * IN + k0,  BsD1);
        __syncthreads();  // vmcnt drain + barrier: tiles visible

        bf16x8 af[4], bfr[4];
#pragma unroll
        for (int t = 0; t < 4; ++t) {
            af[t]  = *(const bf16x8*)&As[(wm + t * 16 + l16) * BK + quad * 8];
            bfr[t] = *(const bf16x8*)&Bs[(wn + t * 16 + l16) * BK + quad * 8];
        }
#pragma unroll
        for (int mt = 0; mt < 4; ++mt)
#pragma unroll
            for (int nt = 0; nt < 4; ++nt)
                acc[mt][nt] = __builtin_amdgcn_mfma_f32_16x16x32_bf16(
                    af[mt], bfr[nt], acc[mt][nt], 0, 0, 0);

        __syncthreads();  // compute done before next overwrite
    }

    // epilogue: C/D layout col=lane&15, row=quad*4+reg; fuse 1-s and clamp
#pragma unroll
    for (int mt = 0; mt < 4; ++mt) {
#pragma unroll
        for (int nt = 0; nt < 4; ++nt) {
#pragma unroll
            for (int r = 0; r < 4; ++r) {
                int row = bm + wm + mt * 16 + quad * 4 + r;
                int col = bn + wn + nt * 16 + l16;
                float v = 1.0f - acc[mt][nt][r];
                C[(size_t)row * OUT + col] = fmaxf(v, 0.0f);
            }
        }
    }
}

extern "C" void kernel_launch(void* const* d_in, const int* in_sizes, int n_in,
                              void* d_out, int out_size, void* d_ws, size_t ws_size,
                              hipStream_t stream) {
    const float* xs = (const float*)d_in[0];       // [4096][1024]
    const float* wt = (const float*)d_in[1];       // [1024][1024]
    float* out = (float*)d_out;                    // [4096][1024]

    unsigned short* A  = (unsigned short*)d_ws;                       // 8 MB
    unsigned short* WT = (unsigned short*)((char*)d_ws + (size_t)Bsz * IN * 2);  // 2 MB

    // prep A: 4096*1024/4 float4s
    prep_a<<<(Bsz * IN / 4 + 255) / 256, 256, 0, stream>>>(xs, A);
    // prep W: sigmoid + transpose
    prep_w<<<dim3(OUT / 32, IN / 32), 256, 0, stream>>>(wt, WT);
    // GEMM
    gemm_fuzzy<<<dim3(OUT / BN, Bsz / BM), 256, 0, stream>>>(A, WT, out);
}

// Round 2
// 89.763 us; speedup vs baseline: 1.0921x; 1.0921x over previous
//
#include <hip/hip_runtime.h>
#include <hip/hip_bf16.h>
#include <math.h>

// FuzzyAND: out[b,j] = max(0, 1 - sum_i sigmoid(W)[i,j] * (1 - xs[b,i]))
// B=4096, IN=1024, OUT=1024, fp32 in/out.
// R2: fused prep; GEMM 128x64x64 tiles (512 blocks = 2/CU), explicit LDS
// double-buffer (1-2 blocks/CU means implicit overlap is absent -> dbuf pays),
// XOR k-swizzle applied on the GLOBAL side (LDS dst must stay lane-linear for
// global_load_lds, m104 constraint).

constexpr int Bsz = 4096;
constexpr int IN  = 1024;
constexpr int OUT = 1024;

constexpr int BM = 128;
constexpr int BN = 64;
constexpr int BK = 64;

typedef __attribute__((ext_vector_type(8))) short bf16x8;  // 8 bf16 = 4 VGPRs
typedef __attribute__((ext_vector_type(4))) float f32x4;

__device__ inline unsigned short f2bf(float f) {
    union { float f; unsigned u; } c{f};
    unsigned lsb = (c.u >> 16) & 1u;
    unsigned r = c.u + 0x7fffu + lsb;   // round-to-nearest-even
    return (unsigned short)(r >> 16);
}

// ---- fused prep: blocks [0,2048) -> A = bf16(1-xs); [2048,3072) -> WT = bf16(sigmoid(W))^T
__global__ void prep_fused(const float* __restrict__ xs, const float* __restrict__ w,
                           unsigned short* __restrict__ A, unsigned short* __restrict__ WT) {
    if (blockIdx.x < 2048) {
        // 8 floats per thread: 2048 blocks * 256 thr * 8 = 4M elements
        int idx = (blockIdx.x * 256 + threadIdx.x) * 2;  // float4 index
        float4 v0 = ((const float4*)xs)[idx];
        float4 v1 = ((const float4*)xs)[idx + 1];
        ushort4 o0, o1;
        o0.x = f2bf(1.0f - v0.x); o0.y = f2bf(1.0f - v0.y);
        o0.z = f2bf(1.0f - v0.z); o0.w = f2bf(1.0f - v0.w);
        o1.x = f2bf(1.0f - v1.x); o1.y = f2bf(1.0f - v1.y);
        o1.z = f2bf(1.0f - v1.z); o1.w = f2bf(1.0f - v1.w);
        ((ushort4*)A)[idx]     = o0;
        ((ushort4*)A)[idx + 1] = o1;
    } else {
        __shared__ unsigned short t[32][33];
        int wblk = blockIdx.x - 2048;
        int o0 = (wblk & 31) * 32, i0 = (wblk >> 5) * 32;
        int tx = threadIdx.x & 31, ty = threadIdx.x >> 5;  // 32 wide x 8 high
#pragma unroll
        for (int r = 0; r < 4; ++r) {
            int row = ty + r * 8;  // i-local
            float v = w[(size_t)(i0 + row) * OUT + o0 + tx];
            float s = 1.0f / (1.0f + __expf(-v));
            t[row][tx] = f2bf(s);
        }
        __syncthreads();
#pragma unroll
        for (int r = 0; r < 4; ++r) {
            int row = ty + r * 8;  // o-local
            WT[(size_t)(o0 + row) * IN + i0 + tx] = t[tx][row];
        }
    }
}

__device__ inline void load_lds16(const unsigned short* g, unsigned short* l) {
    __builtin_amdgcn_global_load_lds(
        (const __attribute__((address_space(1))) void*)g,
        (__attribute__((address_space(3))) void*)l, 16, 0, 0);
}

// ---- GEMM: C[m][n] = max(0, 1 - sum_k A[m][k] * WT[n][k]) ----
// LDS holds swizzled tiles: LDS[row][kb] = G[row][k0 + (kb ^ ((row&7)*8))]
__global__ __launch_bounds__(256) void gemm_fuzzy(const unsigned short* __restrict__ A,
                                                  const unsigned short* __restrict__ Bt,
                                                  float* __restrict__ C) {
    __shared__ unsigned short As[2][BM * BK];  // 2 x 16 KB
    __shared__ unsigned short Bs[2][BN * BK];  // 2 x 8 KB

    const int tid  = threadIdx.x;
    const int lane = tid & 63;
    const int wave = tid >> 6;
    const int quad = lane >> 4;
    const int l16  = lane & 15;
    const int wm   = (wave >> 1) * 64;   // waves tile 2x2 over 128x64
    const int wn   = (wave & 1) * 32;
    const int bm   = blockIdx.y * BM;
    const int bn   = blockIdx.x * BN;

    // ---- staging addresses (chunk c = 16B = 8 bf16) ----
    // A: 1024 chunks (4/thread), B: 512 chunks (2/thread)
    // global k-offset is XOR-swizzled by row so ds_read banks spread;
    // LDS destination stays lane-linear (c*16 bytes).
    const unsigned short* AgSrc[4];
    unsigned short* AgDst[4][2];
#pragma unroll
    for (int r = 0; r < 4; ++r) {
        int c = tid + r * 256;
        int m = c >> 3;
        int gkb = (((c & 7) ^ (m & 7)) << 3);
        AgSrc[r] = A + (size_t)(bm + m) * IN + gkb;
        AgDst[r][0] = &As[0][c << 3];
        AgDst[r][1] = &As[1][c << 3];
    }
    const unsigned short* BgSrc[2];
    unsigned short* BgDst[2][2];
#pragma unroll
    for (int r = 0; r < 2; ++r) {
        int c = tid + r * 256;
        int n = c >> 3;
        int gkb = (((c & 7) ^ (n & 7)) << 3);
        BgSrc[r] = Bt + (size_t)(bn + n) * IN + gkb;
        BgDst[r][0] = &Bs[0][c << 3];
        BgDst[r][1] = &Bs[1][c << 3];
    }

    f32x4 acc[4][2] = {};

    // prefetch tile 0 -> buf 0
#pragma unroll
    for (int r = 0; r < 4; ++r) load_lds16(AgSrc[r], AgDst[r][0]);
#pragma unroll
    for (int r = 0; r < 2; ++r) load_lds16(BgSrc[r], BgDst[r][0]);

    const int NITER = IN / BK;  // 16
    for (int i = 0; i < NITER; ++i) {
        __syncthreads();  // drains vmcnt: buf[i&1] ready; all waves done reading buf[(i+1)&1]

        if (i + 1 < NITER) {
            int k0 = (i + 1) * BK;
            int nb = (i + 1) & 1;
#pragma unroll
            for (int r = 0; r < 4; ++r) load_lds16(AgSrc[r] + k0, AgDst[r][nb]);
#pragma unroll
            for (int r = 0; r < 2; ++r) load_lds16(BgSrc[r] + k0, BgDst[r][nb]);
        }

        const unsigned short* as = As[i & 1];
        const unsigned short* bs = Bs[i & 1];
#pragma unroll
        for (int s = 0; s < 2; ++s) {
            // swizzled k-offset: basek = (s*4+quad)*8, XOR row&7 (= l16&7)
            int koff = ((((s << 2) | quad) ^ (l16 & 7)) << 3);
            bf16x8 af[4], bfr[2];
#pragma unroll
            for (int mt = 0; mt < 4; ++mt)
                af[mt] = *(const bf16x8*)&as[(wm + mt * 16 + l16) * BK + koff];
#pragma unroll
            for (int nt = 0; nt < 2; ++nt)
                bfr[nt] = *(const bf16x8*)&bs[(wn + nt * 16 + l16) * BK + koff];
#pragma unroll
            for (int mt = 0; mt < 4; ++mt)
#pragma unroll
                for (int nt = 0; nt < 2; ++nt)
                    acc[mt][nt] = __builtin_amdgcn_mfma_f32_16x16x32_bf16(
                        af[mt], bfr[nt], acc[mt][nt], 0, 0, 0);
        }
    }

    // epilogue: C/D layout col=lane&15, row=quad*4+reg; fuse 1-s and clamp
#pragma unroll
    for (int mt = 0; mt < 4; ++mt) {
#pragma unroll
        for (int nt = 0; nt < 2; ++nt) {
#pragma unroll
            for (int r = 0; r < 4; ++r) {
                int row = bm + wm + mt * 16 + quad * 4 + r;
                int col = bn + wn + nt * 16 + l16;
                float v = 1.0f - acc[mt][nt][r];
                C[(size_t)row * OUT + col] = fmaxf(v, 0.0f);
            }
        }
    }
}

extern "C" void kernel_launch(void* const* d_in, const int* in_sizes, int n_in,
                              void* d_out, int out_size, void* d_ws, size_t ws_size,
                              hipStream_t stream) {
    const float* xs = (const float*)d_in[0];       // [4096][1024]
    const float* wt = (const float*)d_in[1];       // [1024][1024]
    float* out = (float*)d_out;                    // [4096][1024]

    unsigned short* A  = (unsigned short*)d_ws;                       // 8 MB
    unsigned short* WT = (unsigned short*)((char*)d_ws + (size_t)Bsz * IN * 2);  // 2 MB

    prep_fused<<<2048 + 1024, 256, 0, stream>>>(xs, wt, A, WT);
    gemm_fuzzy<<<dim3(OUT / BN, Bsz / BM), 256, 0, stream>>>(A, WT, out);
}

// Round 3
// 88.381 us; speedup vs baseline: 1.1092x; 1.0156x over previous
//
#include <hip/hip_runtime.h>
#include <hip/hip_bf16.h>
#include <math.h>

// FuzzyAND: out[b,j] = max(0, 1 - sum_i sigmoid(W)[i,j] * (1 - xs[b,i]))
// B=4096, IN=1024, OUT=1024, fp32 in/out.
// R3: AITER-style K-loop — plain global_load->VGPR->ds_write staging (no
// vmcnt(0) drain at barriers, unlike global_load_lds), 2-deep pipeline,
// 64x64 tiles -> 1024 blocks (4/CU), XOR bank swizzle on ds_write side.

constexpr int Bsz = 4096;
constexpr int IN  = 1024;
constexpr int OUT = 1024;

constexpr int BM = 64;
constexpr int BN = 64;
constexpr int BK = 64;

typedef __attribute__((ext_vector_type(8))) short bf16x8;  // 8 bf16 = 4 VGPRs
typedef __attribute__((ext_vector_type(4))) float f32x4;

__device__ inline unsigned short f2bf(float f) {
    union { float f; unsigned u; } c{f};
    unsigned lsb = (c.u >> 16) & 1u;
    unsigned r = c.u + 0x7fffu + lsb;   // round-to-nearest-even
    return (unsigned short)(r >> 16);
}

// ---- fused prep: blocks [0,2048) -> A = bf16(1-xs); [2048,3072) -> WT = bf16(sigmoid(W))^T
__global__ void prep_fused(const float* __restrict__ xs, const float* __restrict__ w,
                           unsigned short* __restrict__ A, unsigned short* __restrict__ WT) {
    if (blockIdx.x < 2048) {
        int idx = (blockIdx.x * 256 + threadIdx.x) * 2;  // float4 index
        float4 v0 = ((const float4*)xs)[idx];
        float4 v1 = ((const float4*)xs)[idx + 1];
        ushort4 o0, o1;
        o0.x = f2bf(1.0f - v0.x); o0.y = f2bf(1.0f - v0.y);
        o0.z = f2bf(1.0f - v0.z); o0.w = f2bf(1.0f - v0.w);
        o1.x = f2bf(1.0f - v1.x); o1.y = f2bf(1.0f - v1.y);
        o1.z = f2bf(1.0f - v1.z); o1.w = f2bf(1.0f - v1.w);
        ((ushort4*)A)[idx]     = o0;
        ((ushort4*)A)[idx + 1] = o1;
    } else {
        __shared__ unsigned short t[32][33];
        int wblk = blockIdx.x - 2048;
        int o0 = (wblk & 31) * 32, i0 = (wblk >> 5) * 32;
        int tx = threadIdx.x & 31, ty = threadIdx.x >> 5;
#pragma unroll
        for (int r = 0; r < 4; ++r) {
            int row = ty + r * 8;  // i-local
            float v = w[(size_t)(i0 + row) * OUT + o0 + tx];
            float s = 1.0f / (1.0f + __expf(-v));
            t[row][tx] = f2bf(s);
        }
        __syncthreads();
#pragma unroll
        for (int r = 0; r < 4; ++r) {
            int row = ty + r * 8;  // o-local
            WT[(size_t)(o0 + row) * IN + i0 + tx] = t[tx][row];
        }
    }
}

// ---- GEMM: C[m][n] = max(0, 1 - sum_k A[m][k] * WT[n][k]) ----
// LDS chunk layout: tile row r (64 bf16 = 8 chunks of 8), chunk kc stored at
// slot r*8 + (kc ^ (r&7))  -> fragment ds_read_b128 spreads all 8 bank groups.
__global__ __launch_bounds__(256, 4) void gemm_fuzzy(const unsigned short* __restrict__ A,
                                                     const unsigned short* __restrict__ Bt,
                                                     float* __restrict__ C) {
    __shared__ unsigned short As[2][BM * BK];  // 2 x 8 KB
    __shared__ unsigned short Bs[2][BN * BK];  // 2 x 8 KB

    const int tid  = threadIdx.x;
    const int lane = tid & 63;
    const int wave = tid >> 6;
    const int quad = lane >> 4;
    const int l16  = lane & 15;
    const int wm   = (wave >> 1) * 32;   // waves tile 2x2 over 64x64
    const int wn   = (wave & 1) * 32;
    const int bm   = blockIdx.y * BM;
    const int bn   = blockIdx.x * BN;

    // staging: 512 chunks (16B) per tile, 2 per thread: c0=tid, c1=tid+256
    const int c0 = tid, c1 = tid + 256;
    const int ar0 = c0 >> 3, ak0 = c0 & 7;
    const int ar1 = c1 >> 3, ak1 = c1 & 7;
    const unsigned short* Ag0 = A  + (size_t)(bm + ar0) * IN + ak0 * 8;
    const unsigned short* Ag1 = A  + (size_t)(bm + ar1) * IN + ak1 * 8;
    const unsigned short* Bg0 = Bt + (size_t)(bn + ar0) * IN + ak0 * 8;
    const unsigned short* Bg1 = Bt + (size_t)(bn + ar1) * IN + ak1 * 8;
    const int ad0 = ((c0 & ~7) | (ak0 ^ (ar0 & 7))) * 8;  // swizzled ushort index
    const int ad1 = ((c1 & ~7) | (ak1 ^ (ar1 & 7))) * 8;

    bf16x8 rA[2][2], rB[2][2];

    // prologue: G0 -> regs -> LDS0 ; G1 -> regs
    rA[0][0] = *(const bf16x8*)Ag0; rA[0][1] = *(const bf16x8*)Ag1;
    rB[0][0] = *(const bf16x8*)Bg0; rB[0][1] = *(const bf16x8*)Bg1;
    *(bf16x8*)&As[0][ad0] = rA[0][0]; *(bf16x8*)&As[0][ad1] = rA[0][1];
    *(bf16x8*)&Bs[0][ad0] = rB[0][0]; *(bf16x8*)&Bs[0][ad1] = rB[0][1];
    rA[1][0] = *(const bf16x8*)(Ag0 + BK); rA[1][1] = *(const bf16x8*)(Ag1 + BK);
    rB[1][0] = *(const bf16x8*)(Bg0 + BK); rB[1][1] = *(const bf16x8*)(Bg1 + BK);
    __syncthreads();

    f32x4 acc[2][2] = {};
    const int NIT = IN / BK;  // 16

#pragma unroll
    for (int i = 0; i < NIT; ++i) {
        // issue loads for tile i+2 into the reg set freed at iter i-1
        if (i + 2 < NIT) {
            int k0 = (i + 2) * BK;
            rA[i & 1][0] = *(const bf16x8*)(Ag0 + k0);
            rA[i & 1][1] = *(const bf16x8*)(Ag1 + k0);
            rB[i & 1][0] = *(const bf16x8*)(Bg0 + k0);
            rB[i & 1][1] = *(const bf16x8*)(Bg1 + k0);
        }

        const unsigned short* as = As[i & 1];
        const unsigned short* bs = Bs[i & 1];
#pragma unroll
        for (int s = 0; s < 2; ++s) {
            const int kc = s * 4 + quad;
            bf16x8 af[2], bfr[2];
#pragma unroll
            for (int mt = 0; mt < 2; ++mt) {
                int row = wm + mt * 16 + l16;
                af[mt] = *(const bf16x8*)&as[(row * 8 + (kc ^ (row & 7))) * 8];
            }
#pragma unroll
            for (int nt = 0; nt < 2; ++nt) {
                int row = wn + nt * 16 + l16;
                bfr[nt] = *(const bf16x8*)&bs[(row * 8 + (kc ^ (row & 7))) * 8];
            }
#pragma unroll
            for (int mt = 0; mt < 2; ++mt)
#pragma unroll
                for (int nt = 0; nt < 2; ++nt)
                    acc[mt][nt] = __builtin_amdgcn_mfma_f32_16x16x32_bf16(
                        af[mt], bfr[nt], acc[mt][nt], 0, 0, 0);
        }

        // stage tile i+1 (already in regs, loaded a full iteration ago) -> LDS
        if (i + 1 < NIT) {
            int nb = (i + 1) & 1;
            *(bf16x8*)&As[nb][ad0] = rA[nb][0]; *(bf16x8*)&As[nb][ad1] = rA[nb][1];
            *(bf16x8*)&Bs[nb][ad0] = rB[nb][0]; *(bf16x8*)&Bs[nb][ad1] = rB[nb][1];
        }
        __syncthreads();  // lgkmcnt drain only — VGPR loads stay in flight
    }

    // epilogue: C/D layout col=lane&15, row=quad*4+reg; fuse 1-s and clamp
#pragma unroll
    for (int mt = 0; mt < 2; ++mt) {
#pragma unroll
        for (int nt = 0; nt < 2; ++nt) {
#pragma unroll
            for (int r = 0; r < 4; ++r) {
                int row = bm + wm + mt * 16 + quad * 4 + r;
                int col = bn + wn + nt * 16 + l16;
                float v = 1.0f - acc[mt][nt][r];
                C[(size_t)row * OUT + col] = fmaxf(v, 0.0f);
            }
        }
    }
}

extern "C" void kernel_launch(void* const* d_in, const int* in_sizes, int n_in,
                              void* d_out, int out_size, void* d_ws, size_t ws_size,
                              hipStream_t stream) {
    const float* xs = (const float*)d_in[0];       // [4096][1024]
    const float* wt = (const float*)d_in[1];       // [1024][1024]
    float* out = (float*)d_out;                    // [4096][1024]

    unsigned short* A  = (unsigned short*)d_ws;                       // 8 MB
    unsigned short* WT = (unsigned short*)((char*)d_ws + (size_t)Bsz * IN * 2);  // 2 MB

    prep_fused<<<2048 + 1024, 256, 0, stream>>>(xs, wt, A, WT);
    gemm_fuzzy<<<dim3(OUT / BN, Bsz / BM), 256, 0, stream>>>(A, WT, out);
}